// Round 1
// baseline (220.460 us; speedup 1.0000x reference)
//
#include <hip/hip_runtime.h>

// SPGG Q-learning step on a 2048x2048 torus — SINGLE fused kernel, v2.
//
// v1 (79 us/dispatch) was latency-exposed: hbm 27% of peak, VALU 35%,
// VGPR_Count=16 (compiler serialized to minimize regs; ldir->nidx->gather
// chain sat naked at the tail). Two changes, both numerics-preserving:
//
// 1. Load hoisting: ldir/lp/Q[idx]/tmin[idx] issue first; the neighbor
//    gathers Q[nidx]/tmin[nidx] issue BEFORE the first barrier so their
//    latency hides under tile staging + b-precompute + both barriers.
//
// 2. Shared base-value precompute: b(cell) = (float)coop_num * KB is used
//    by the plus-stencils of the cell and all 4 neighbors, and again by the
//    neighbor-profit recompute — ~10x redundancy per block in v1. Now
//    computed once per cell into btile[5][260] (int adds are order-exact;
//    the single __fmul_rn is the reference's op). Each profit is then
//    5 LDS float reads + the reference's exact __fadd_rn/__fsub_rn chain —
//    bit-identical to v1's values, ~40% less VALU+LDS work per thread.
//
// Numerics: identical op sequence to the passing v1 (cn int-sum order is
// exact; b/s0/s1/upd/fermi use the same __f*_rn ops in the same order;
// exp in double, rounded once).

#define LSIDE 2048
#define LMASK 2047
#define LSHIFT 11
#define NCELL (LSIDE * LSIDE)

#define TROWS 7
#define TCOLS 264   // 256 + 2*4 halo (4-aligned); 264*4B row = 16B-aligned
#define BROWS 5     // b rows i-2..i+2
#define BCOLS 260   // b cols j0-2..j0+257

__global__ __launch_bounds__(256) void spgg_fused(
    const int* __restrict__ tmin,   // type_t_minus
    const int* __restrict__ tt,     // type_t
    const float* __restrict__ Q,    // Q_tensor [N,4]
    const int* __restrict__ ldir,   // learning_direction
    const float* __restrict__ lp,   // learning_probabilities
    float* __restrict__ Qn,         // out: Q_new [N,4]
    float* __restrict__ prof,       // out: profit [N]
    float* __restrict__ t1out)      // out: type_t1 [N]
{
    __shared__ int   tile[TROWS][TCOLS];
    __shared__ float btile[BROWS][BCOLS];   // b = (float)coop_num * KB per cell

    const int t   = threadIdx.x;
    const int blk = blockIdx.x;
    const int i   = blk >> 3;            // 8 blocks per lattice row
    const int j0  = (blk & 7) << 8;      // 256 cells per block
    const int j   = j0 + t;
    const int idx = (i << LSHIFT) + j;

    // ---- early independent loads (keep in flight across staging+barriers) ----
    const int    dir = ldir[idx];
    const float  pv  = lp[idx];
    const float4 qr  = ((const float4*)Q)[idx];
    const int    A   = tmin[idx];

    // ---- stage tt tile + halo into LDS (coalesced int4, wrapped) ----
    for (int k = t; k < TROWS * (TCOLS / 4); k += 256) {
        int r = k / (TCOLS / 4);
        int m = k - r * (TCOLS / 4);
        int row_g = (i + r - 3) & LMASK;
        int col_g = (j0 - 4 + (m << 2)) & LMASK;   // multiple of 4 -> aligned
        int4 v = *(const int4*)&tt[(row_g << LSHIFT) + col_g];
        *(int4*)&tile[r][m << 2] = v;
    }

    // ---- neighbor address + EARLY gather issue (overlaps barriers below) ----
    // dir: 0=left(j-1) 1=right(j+1) 2=up(i-1) 3=down(i+1)
    const int di = (dir == 3) - (dir == 2);
    const int dj = (dir == 1) - (dir == 0);
    const int ni = (i + di) & LMASK;
    const int nj = (j + dj) & LMASK;
    const int nidx = (ni << LSHIFT) + nj;
    const float4 qn4 = ((const float4*)Q)[nidx];
    const int    An  = tmin[nidx];

    __syncthreads();

    const float KB        = 0.5554f;  // float32(R / 5.0)
    const float ETA       = 0.8f;
    const float ONE_M_ETA = 0.2f;     // float32(1.0 - 0.8)
    const float GAMMA     = 0.8f;

    // ---- b-precompute: one coop_num*KB per cell, shared by all stencils ----
    // btile[r][c] corresponds to global cell (i-2+r, j0-2+c);
    // tile coords of that cell: (r+1, c+2). tt values are {0,1} so the
    // cooperator mask IS the value; int-add order is exact (no rounding).
    auto bval = [&](int tr, int tc) -> float {
        int cn = tile[tr][tc] + tile[tr-1][tc] + tile[tr+1][tc]
               + tile[tr][tc-1] + tile[tr][tc+1];
        return __fmul_rn((float)cn, KB);
    };
    #pragma unroll
    for (int r = 0; r < BROWS; ++r)
        btile[r][t] = bval(r + 1, t + 2);
    if (t < BCOLS - 256) {              // 4 leftover columns
        #pragma unroll
        for (int r = 0; r < BROWS; ++r)
            btile[r][256 + t] = bval(r + 1, 258 + t);
    }
    __syncthreads();

    // profit of the cell at btile coords (r,c) — reference's exact op order:
    // plus_sum order is (c, i-1, i+1, j-1, j+1); s1 subtracts 1.0 per term.
    auto profit_from_b = [&](int r, int c, int coop) -> float {
        float b_c = btile[r][c];
        float b_u = btile[r-1][c];
        float b_d = btile[r+1][c];
        float b_l = btile[r][c-1];
        float b_r = btile[r][c+1];
        float s0 = __fadd_rn(__fadd_rn(__fadd_rn(__fadd_rn(b_c, b_u), b_d), b_l), b_r);
        float s1 = __fadd_rn(__fadd_rn(__fadd_rn(__fadd_rn(
                       __fsub_rn(b_c, 1.0f), __fsub_rn(b_u, 1.0f)),
                       __fsub_rn(b_d, 1.0f)), __fsub_rn(b_l, 1.0f)),
                       __fsub_rn(b_r, 1.0f));
        return coop ? s1 : s0;
    };

    // Q-learning update value — exact reference op order.
    auto upd_of = [&](float profit, float4 q4, int Ai, int Bi) -> float {
        float q0 = (Bi == 0) ? q4.x : q4.z;
        float q1 = (Bi == 0) ? q4.y : q4.w;
        float mx = fmaxf(q0, q1);
        int k = Ai * 2 + Bi;
        float old = (k == 0) ? q4.x : ((k == 1) ? q4.y : ((k == 2) ? q4.z : q4.w));
        float t0 = __fmul_rn(GAMMA, mx);
        float t1 = __fadd_rn(profit, t0);
        float t2 = __fmul_rn(ETA, t1);
        float t3 = __fmul_rn(ONE_M_ETA, old);
        return __fadd_rn(t3, t2);
    };

    // ---- own cell: profit + Q update ----
    const int B     = tile[3][t + 4];
    float p_own = profit_from_b(2, t + 2, B);
    float upd   = upd_of(p_own, qr, A, B);

    int k = A * 2 + B;
    float4 qo;
    qo.x = (k == 0) ? upd : qr.x;
    qo.y = (k == 1) ? upd : qr.y;
    qo.z = (k == 2) ? upd : qr.z;
    qo.w = (k == 3) ? upd : qr.w;
    ((float4*)Qn)[idx] = qo;
    prof[idx] = p_own;

    // ---- fermi: recompute the selected neighbor's upd, bit-identically ----
    const int Bn = tile[3 + di][t + 4 + dj];
    float p_nb   = profit_from_b(2 + di, t + 2 + dj, Bn);
    float upd_nb = upd_of(p_nb, qn4, An, Bn);

    float e1 = __fsub_rn(upd, upd_nb);
    float e2 = __fmul_rn(e1, 2.0f);           // / K_FERMI(0.5) exactly
    float ex = (float)exp((double)e2);        // same as passing rounds
    float W  = __fdiv_rn(1.0f, __fadd_rn(1.0f, ex));
    int sel = (pv <= W) ? Bn : B;
    t1out[idx] = (float)sel;
}

extern "C" void kernel_launch(void* const* d_in, const int* in_sizes, int n_in,
                              void* d_out, int out_size, void* d_ws, size_t ws_size,
                              hipStream_t stream) {
    const int*   type_t_minus = (const int*)d_in[0];
    const int*   type_t       = (const int*)d_in[1];
    const float* Q_tensor     = (const float*)d_in[2];
    const int*   ldir         = (const int*)d_in[3];
    const float* lprob        = (const float*)d_in[4];

    float* out   = (float*)d_out;
    float* Qn    = out;                       // [N*4]
    float* t1out = out + (size_t)4 * NCELL;   // [N]
    float* prof  = out + (size_t)5 * NCELL;   // [N]

    const int threads = 256;
    const int blocks  = NCELL / threads;      // 16384 (8 blocks per row)
    spgg_fused<<<blocks, threads, 0, stream>>>(type_t_minus, type_t, Q_tensor,
                                               ldir, lprob, Qn, prof, t1out);
}

// Round 2
// 211.356 us; speedup vs baseline: 1.0431x; 1.0431x over previous
//
#include <hip/hip_runtime.h>

// SPGG Q-learning step on a 2048x2048 torus — SINGLE fused kernel, v3.
//
// v2 post-mortem (74.8 us): VALU 31.5%, LDS pipe ~35%, HBM 28% — no pipe
// saturated. The kernel is barrier-convoyed with one short serial chain per
// thread (stage -> full vmcnt drain -> btile -> barrier -> profit/upd ->
// ~300-cycle dependent f64 exp -> store). Fixed overhead (7 halo rows per
// compute row, 2 barriers, addressing) is paid per single cell.
//
// v3: each block computes a 2x256 strip (2 vertically-adjacent cells per
// thread). Effects:
//   - staged tt rows per compute-row: 7 -> 4 (8 rows for 2 cell-rows);
//   - btile b-values per cell: 10.2 -> 6.1;
//   - barriers per cell halved;
//   - two fully independent per-cell chains (profit/upd/exp/store) per
//     thread -> ILP x2, the f64 exp latencies interleave.
//
// Numerics: identical op sequence per cell as the passing v1/v2 (int-exact
// coop sums; __f*_rn ops in the reference's exact order; exp in double,
// rounded once).

#define LSIDE 2048
#define LMASK 2047
#define LSHIFT 11
#define NCELL (LSIDE * LSIDE)

#define TROWS 8     // rows i0-3 .. i0+4
#define TCOLS 264   // 256 + 2*4 halo (4-aligned); 264*4B row = 16B-aligned
#define BROWS 6     // b rows i0-2 .. i0+3
#define BCOLS 260   // b cols j0-2 .. j0+257

__global__ __launch_bounds__(256) void spgg_fused(
    const int* __restrict__ tmin,   // type_t_minus
    const int* __restrict__ tt,     // type_t
    const float* __restrict__ Q,    // Q_tensor [N,4]
    const int* __restrict__ ldir,   // learning_direction
    const float* __restrict__ lp,   // learning_probabilities
    float* __restrict__ Qn,         // out: Q_new [N,4]
    float* __restrict__ prof,       // out: profit [N]
    float* __restrict__ t1out)      // out: type_t1 [N]
{
    __shared__ int   tile[TROWS][TCOLS];
    __shared__ float btile[BROWS][BCOLS];   // b = (float)coop_num * KB

    const int t   = threadIdx.x;
    const int blk = blockIdx.x;
    const int i0  = (blk >> 3) << 1;     // 2 lattice rows per block
    const int j0  = (blk & 7) << 8;      // 256 cells per block-row
    const int j   = j0 + t;
    const int idx0 = (i0 << LSHIFT) + j;
    const int idx1 = idx0 + LSIDE;       // row i0+1, same column

    // ---- early independent loads (all issue before the barrier drain) ----
    const int    dir0 = ldir[idx0];
    const int    dir1 = ldir[idx1];
    const float  pv0  = lp[idx0];
    const float  pv1  = lp[idx1];
    const float4 qr0  = ((const float4*)Q)[idx0];
    const float4 qr1  = ((const float4*)Q)[idx1];
    const int    A0   = tmin[idx0];
    const int    A1   = tmin[idx1];

    // ---- stage tt tile + halo into LDS (coalesced int4, wrapped) ----
    for (int k = t; k < TROWS * (TCOLS / 4); k += 256) {
        int r = k / (TCOLS / 4);
        int m = k - r * (TCOLS / 4);
        int row_g = (i0 + r - 3) & LMASK;
        int col_g = (j0 - 4 + (m << 2)) & LMASK;   // multiple of 4 -> aligned
        int4 v = *(const int4*)&tt[(row_g << LSHIFT) + col_g];
        *(int4*)&tile[r][m << 2] = v;
    }

    // ---- neighbor addresses + gathers (overlap the barrier drain) ----
    // dir: 0=left(j-1) 1=right(j+1) 2=up(i-1) 3=down(i+1)
    const int di0 = (dir0 == 3) - (dir0 == 2);
    const int dj0 = (dir0 == 1) - (dir0 == 0);
    const int nidx0 = ((((i0 + di0) & LMASK)) << LSHIFT) + ((j + dj0) & LMASK);
    const float4 qn0 = ((const float4*)Q)[nidx0];
    const int    An0 = tmin[nidx0];

    const int di1 = (dir1 == 3) - (dir1 == 2);
    const int dj1 = (dir1 == 1) - (dir1 == 0);
    const int nidx1 = ((((i0 + 1 + di1) & LMASK)) << LSHIFT) + ((j + dj1) & LMASK);
    const float4 qn1 = ((const float4*)Q)[nidx1];
    const int    An1 = tmin[nidx1];

    __syncthreads();

    const float KB        = 0.5554f;  // float32(R / 5.0)
    const float ETA       = 0.8f;
    const float ONE_M_ETA = 0.2f;     // float32(1.0 - 0.8)
    const float GAMMA     = 0.8f;

    // ---- b-precompute: one coop_num*KB per cell, shared by all stencils ----
    // btile[r][c] <-> global cell (i0-2+r, j0-2+c); tile coords (r+1, c+2).
    // tt values are {0,1} so the cooperator mask IS the value; the int-add
    // order is exact (no rounding); single __fmul_rn is the reference op.
    auto bval = [&](int tr, int tc) -> float {
        int cn = tile[tr][tc] + tile[tr-1][tc] + tile[tr+1][tc]
               + tile[tr][tc-1] + tile[tr][tc+1];
        return __fmul_rn((float)cn, KB);
    };
    #pragma unroll
    for (int r = 0; r < BROWS; ++r)
        btile[r][t] = bval(r + 1, t + 2);
    if (t < BCOLS - 256) {              // 4 leftover columns
        #pragma unroll
        for (int r = 0; r < BROWS; ++r)
            btile[r][256 + t] = bval(r + 1, 258 + t);
    }
    __syncthreads();

    // profit at btile coords (r,c) — reference's exact op order:
    // plus_sum order (c, i-1, i+1, j-1, j+1); s1 subtracts 1.0 per term.
    auto profit_from_b = [&](int r, int c, int coop) -> float {
        float b_c = btile[r][c];
        float b_u = btile[r-1][c];
        float b_d = btile[r+1][c];
        float b_l = btile[r][c-1];
        float b_r = btile[r][c+1];
        float s0 = __fadd_rn(__fadd_rn(__fadd_rn(__fadd_rn(b_c, b_u), b_d), b_l), b_r);
        float s1 = __fadd_rn(__fadd_rn(__fadd_rn(__fadd_rn(
                       __fsub_rn(b_c, 1.0f), __fsub_rn(b_u, 1.0f)),
                       __fsub_rn(b_d, 1.0f)), __fsub_rn(b_l, 1.0f)),
                       __fsub_rn(b_r, 1.0f));
        return coop ? s1 : s0;
    };

    // Q-learning update value — exact reference op order.
    auto upd_of = [&](float profit, float4 q4, int Ai, int Bi) -> float {
        float q0 = (Bi == 0) ? q4.x : q4.z;
        float q1 = (Bi == 0) ? q4.y : q4.w;
        float mx = fmaxf(q0, q1);
        int k = Ai * 2 + Bi;
        float old = (k == 0) ? q4.x : ((k == 1) ? q4.y : ((k == 2) ? q4.z : q4.w));
        float t0 = __fmul_rn(GAMMA, mx);
        float t1 = __fadd_rn(profit, t0);
        float t2 = __fmul_rn(ETA, t1);
        float t3 = __fmul_rn(ONE_M_ETA, old);
        return __fadd_rn(t3, t2);
    };

    // ---- cell 0: (i0, j) -> tile row 3, btile row 2 ----
    const int B0    = tile[3][t + 4];
    float p_own0    = profit_from_b(2, t + 2, B0);
    float upd0      = upd_of(p_own0, qr0, A0, B0);

    // ---- cell 1: (i0+1, j) -> tile row 4, btile row 3 ----
    const int B1    = tile[4][t + 4];
    float p_own1    = profit_from_b(3, t + 2, B1);
    float upd1      = upd_of(p_own1, qr1, A1, B1);

    // ---- Q writes ----
    int k0 = A0 * 2 + B0;
    float4 qo0;
    qo0.x = (k0 == 0) ? upd0 : qr0.x;
    qo0.y = (k0 == 1) ? upd0 : qr0.y;
    qo0.z = (k0 == 2) ? upd0 : qr0.z;
    qo0.w = (k0 == 3) ? upd0 : qr0.w;
    ((float4*)Qn)[idx0] = qo0;
    prof[idx0] = p_own0;

    int k1 = A1 * 2 + B1;
    float4 qo1;
    qo1.x = (k1 == 0) ? upd1 : qr1.x;
    qo1.y = (k1 == 1) ? upd1 : qr1.y;
    qo1.z = (k1 == 2) ? upd1 : qr1.z;
    qo1.w = (k1 == 3) ? upd1 : qr1.w;
    ((float4*)Qn)[idx1] = qo1;
    prof[idx1] = p_own1;

    // ---- fermi: recompute selected neighbors' upd, bit-identically ----
    // Two independent chains — the f64 exp latencies interleave.
    const int Bn0 = tile[3 + di0][t + 4 + dj0];
    float p_nb0   = profit_from_b(2 + di0, t + 2 + dj0, Bn0);
    float upd_nb0 = upd_of(p_nb0, qn0, An0, Bn0);

    const int Bn1 = tile[4 + di1][t + 4 + dj1];
    float p_nb1   = profit_from_b(3 + di1, t + 2 + dj1, Bn1);
    float upd_nb1 = upd_of(p_nb1, qn1, An1, Bn1);

    float e10 = __fsub_rn(upd0, upd_nb0);
    float e20 = __fmul_rn(e10, 2.0f);          // / K_FERMI(0.5) exactly
    float e11 = __fsub_rn(upd1, upd_nb1);
    float e21 = __fmul_rn(e11, 2.0f);
    float ex0 = (float)exp((double)e20);       // same as passing rounds
    float ex1 = (float)exp((double)e21);
    float W0  = __fdiv_rn(1.0f, __fadd_rn(1.0f, ex0));
    float W1  = __fdiv_rn(1.0f, __fadd_rn(1.0f, ex1));
    int sel0 = (pv0 <= W0) ? Bn0 : B0;
    int sel1 = (pv1 <= W1) ? Bn1 : B1;
    t1out[idx0] = (float)sel0;
    t1out[idx1] = (float)sel1;
}

extern "C" void kernel_launch(void* const* d_in, const int* in_sizes, int n_in,
                              void* d_out, int out_size, void* d_ws, size_t ws_size,
                              hipStream_t stream) {
    const int*   type_t_minus = (const int*)d_in[0];
    const int*   type_t       = (const int*)d_in[1];
    const float* Q_tensor     = (const float*)d_in[2];
    const int*   ldir         = (const int*)d_in[3];
    const float* lprob        = (const float*)d_in[4];

    float* out   = (float*)d_out;
    float* Qn    = out;                       // [N*4]
    float* t1out = out + (size_t)4 * NCELL;   // [N]
    float* prof  = out + (size_t)5 * NCELL;   // [N]

    const int threads = 256;
    const int blocks  = NCELL / (threads * 2);  // 8192 (2 rows x 256 cols each)
    spgg_fused<<<blocks, threads, 0, stream>>>(type_t_minus, type_t, Q_tensor,
                                               ldir, lprob, Qn, prof, t1out);
}